// Round 7
// baseline (185.142 us; speedup 1.0000x reference)
//
#include <hip/hip_runtime.h>

#define H_NUM 16
#define HD    64
#define SQ    2048
#define HID   1024
#define MTOK  8192   // B*S

typedef __attribute__((ext_vector_type(8))) short bf16x8;
typedef __attribute__((ext_vector_type(4))) short s16x4;
typedef __attribute__((ext_vector_type(4))) float f32x4;

__device__ __forceinline__ short f2bf(float f) {
  union { float f; unsigned u; } v; v.f = f;
  unsigned r = v.u + 0x7fffu + ((v.u >> 16) & 1u);
  return (short)(r >> 16);
}

__device__ __forceinline__ float fexp2(float x) {
#if __has_builtin(__builtin_amdgcn_exp2f)
  return __builtin_amdgcn_exp2f(x);
#else
  return exp2f(x);
#endif
}

__device__ __forceinline__ void gload_lds16(const short* g, short* l) {
  __builtin_amdgcn_global_load_lds(
      (const __attribute__((address_space(1))) void*)g,
      (__attribute__((address_space(3))) void*)l, 16, 0, 0);
}

// ---------- converters ----------
__global__ void k_cvt(const float* __restrict__ in, short* __restrict__ out, int n4) {
  int i = blockIdx.x * blockDim.x + threadIdx.x;
  if (i < n4) {
    float4 f = ((const float4*)in)[i];
    s16x4 o = { f2bf(f.x), f2bf(f.y), f2bf(f.z), f2bf(f.w) };
    ((s16x4*)out)[i] = o;
  }
}

// out[c][r] = bf16(in[r][c]);  R,C multiples of 32; block (32,8)
__global__ void k_tr(const float* __restrict__ in, short* __restrict__ out, int R, int C) {
  __shared__ float t[32][33];
  int c0 = blockIdx.x * 32, r0 = blockIdx.y * 32;
  int tx = threadIdx.x, ty = threadIdx.y;
#pragma unroll
  for (int i = 0; i < 4; i++)
    t[ty + 8 * i][tx] = in[(size_t)(r0 + ty + 8 * i) * C + c0 + tx];
  __syncthreads();
#pragma unroll
  for (int i = 0; i < 4; i++)
    out[(size_t)(c0 + ty + 8 * i) * R + r0 + tx] = f2bf(t[tx][ty + 8 * i]);
}

// ---------- GEMM: C[M,N] = A[M,K] @ Bt[N,K]^T + bias ----------
// 256x128 tile, BK=64, 8 waves (4M x 2N, 64x64 out each).
// TRIPLE-buffered LDS (144KB), 4 phases per K-tile (phase = (kk, n-half)):
//   {2-6 ds_read | 2 gload_lds of tile t+2 | barrier | lgkmcnt(0) |
//    sched_barrier | setprio(1) 8 MFMA setprio(0) | barrier}
// vmcnt(6) at tile boundary only (counted, never 0 mid-loop). T1/T2/T5.
template <int EPI>
__global__ __launch_bounds__(512, 2) void k_gemm(
    const short* __restrict__ A, const short* __restrict__ Bt,
    const float* __restrict__ bias,
    short* __restrict__ qbuf, short* __restrict__ kbuf, short* __restrict__ vtbuf,
    float* __restrict__ outf, int Kd) {
  __shared__ short as[3][16384];  // 3 x [256][64]
  __shared__ short bs[3][8192];   // 3 x [128][64]
  const int tid = threadIdx.x;
  const int w = tid >> 6, l = tid & 63;
  const int lr = l & 15, lk = l >> 4;
  const int wm = w >> 1, wn = w & 1;
  // bijective XCD swizzle (nwg % 8 == 0 for both launches)
  const int nwg = gridDim.x * gridDim.y;
  const int lin = blockIdx.y * gridDim.x + blockIdx.x;
  const int swz = (lin & 7) * (nwg >> 3) + (lin >> 3);
  const int m0 = (swz / gridDim.x) * 256, n0 = (swz % gridDim.x) * 128;

  const int NT = Kd >> 6;   // 16

  // staging granule: g covers row g>>3, col-group g&7 (source pre-swizzled,
  // LDS linear, read applies same XOR)  [m173 / rule #21]
#define STAGE_A(kt_, bufn_, rnd_)                                         \
  {                                                                       \
    int g = (rnd_) * 512 + tid;                                           \
    int row = g >> 3;                                                     \
    int sc_ = ((g & 7) * 8) ^ ((row & 7) * 8);                            \
    gload_lds16(A + (size_t)(m0 + row) * Kd + (kt_) + sc_,                \
                &as[bufn_][0] + g * 8);                                   \
  }
#define STAGE_B(kt_, bufn_, rnd_)                                         \
  {                                                                       \
    int g = (rnd_) * 512 + tid;                                           \
    int row = g >> 3;                                                     \
    int sc_ = ((g & 7) * 8) ^ ((row & 7) * 8);                            \
    gload_lds16(Bt + (size_t)(n0 + row) * Kd + (kt_) + sc_,               \
                &bs[bufn_][0] + g * 8);                                   \
  }

  f32x4 acc[4][4] = {};
  const int cswz = (lr & 7) * 8;

  // prologue: stage tiles 0 and 1; wait tile 0 (6 newest stay in flight)
  STAGE_A(0, 0, 0) STAGE_A(0, 0, 1) STAGE_A(0, 0, 2) STAGE_A(0, 0, 3)
  STAGE_B(0, 0, 0) STAGE_B(0, 0, 1)
  STAGE_A(64, 1, 0) STAGE_A(64, 1, 1) STAGE_A(64, 1, 2) STAGE_A(64, 1, 3)
  STAGE_B(64, 1, 0) STAGE_B(64, 1, 1)
  asm volatile("s_waitcnt vmcnt(6)" ::: "memory");
  __builtin_amdgcn_s_barrier();

  int bufR = 0;
  for (int t = 0; t < NT; ++t) {
    const short* ab = &as[bufR][0];
    const short* bb = &bs[bufR][0];
    int bufS = bufR + 2; if (bufS >= 3) bufS -= 3;
    const bool st = (t + 2 < NT);
    const int ktn = (t + 2) * 64;

    bf16x8 af[4], bfr[2];
#pragma unroll
    for (int p = 0; p < 4; ++p) {
      const int kk = p >> 1, nh = p & 1;
      // ds-load register subtiles for this phase
      if (nh == 0) {
#pragma unroll
        for (int m = 0; m < 4; ++m)
          af[m] = *(const bf16x8*)(ab + (wm * 64 + m * 16 + lr) * 64 +
                                   ((kk * 32 + lk * 8) ^ cswz));
      }
#pragma unroll
      for (int n = 0; n < 2; ++n)
        bfr[n] = *(const bf16x8*)(bb + (wn * 64 + (nh * 2 + n) * 16 + lr) * 64 +
                                  ((kk * 32 + lk * 8) ^ cswz));
      // stage 2 granules of tile t+2 (phases 0-2)
      if (st) {
        if (p == 0) { STAGE_A(ktn, bufS, 0) STAGE_A(ktn, bufS, 1) }
        if (p == 1) { STAGE_A(ktn, bufS, 2) STAGE_A(ktn, bufS, 3) }
        if (p == 2) { STAGE_B(ktn, bufS, 0) STAGE_B(ktn, bufS, 1) }
      }
      // tile boundary: retire tile t+1's 6 loads, keep t+2's 6 in flight
      if (p == 3) {
        if (t < NT - 2) asm volatile("s_waitcnt vmcnt(6)" ::: "memory");
        else            asm volatile("s_waitcnt vmcnt(0)" ::: "memory");
      }
      __builtin_amdgcn_s_barrier();
      asm volatile("s_waitcnt lgkmcnt(0)" ::: "memory");
      __builtin_amdgcn_sched_barrier(0);
      __builtin_amdgcn_s_setprio(1);
#pragma unroll
      for (int m = 0; m < 4; ++m)
#pragma unroll
        for (int n = 0; n < 2; ++n)
          acc[m][nh * 2 + n] = __builtin_amdgcn_mfma_f32_16x16x32_bf16(
              af[m], bfr[n], acc[m][nh * 2 + n], 0, 0, 0);
      __builtin_amdgcn_s_setprio(0);
      __builtin_amdgcn_s_barrier();
    }
    bufR = (bufR == 2) ? 0 : bufR + 1;
  }
#undef STAGE_A
#undef STAGE_B

  // C layout: col=lane&15, row=(lane>>4)*4+reg  [m89]
  const float SCLQ = 0.125f * 1.44269504088896341f;
#pragma unroll
  for (int n = 0; n < 4; ++n) {
    const int col = n0 + wn * 64 + n * 16 + lr;
    const float bv = bias[col];
    if (EPI == 1) {
#pragma unroll
      for (int m = 0; m < 4; ++m) {
        int row = m0 + wm * 64 + m * 16 + lk * 4;
#pragma unroll
        for (int r = 0; r < 4; ++r)
          outf[(size_t)(row + r) * HID + col] = acc[m][n][r] + bv;
      }
    } else if (col < HID) {  // K: [BH][S][D]
      int h = col >> 6, d = col & 63;
#pragma unroll
      for (int m = 0; m < 4; ++m) {
        int row = m0 + wm * 64 + m * 16 + lk * 4;
        int b = row >> 11, s = row & 2047;
#pragma unroll
        for (int r = 0; r < 4; ++r)
          kbuf[((size_t)(b * H_NUM + h) * SQ + s + r) * HD + d] = f2bf(acc[m][n][r] + bv);
      }
    } else if (col < 2 * HID) {  // V^T: [BH][D][S], packed 4-s stores
      int f = col - HID, h = f >> 6, d = f & 63;
#pragma unroll
      for (int m = 0; m < 4; ++m) {
        int row = m0 + wm * 64 + m * 16 + lk * 4;
        int b = row >> 11, s = row & 2047;
        s16x4 pk;
#pragma unroll
        for (int r = 0; r < 4; ++r) pk[r] = f2bf(acc[m][n][r] + bv);
        *(s16x4*)&vtbuf[((size_t)(b * H_NUM + h) * HD + d) * SQ + s] = pk;
      }
    } else {  // Q: [BH][S][D], pre-scaled into exp2 domain
      int f = col - 2 * HID, h = f >> 6, d = f & 63;
#pragma unroll
      for (int m = 0; m < 4; ++m) {
        int row = m0 + wm * 64 + m * 16 + lk * 4;
        int b = row >> 11, s = row & 2047;
#pragma unroll
        for (int r = 0; r < 4; ++r)
          qbuf[((size_t)(b * H_NUM + h) * SQ + s + r) * HD + d] = f2bf((acc[m][n][r] + bv) * SCLQ);
      }
    }
  }
}

// ---------- flash attention, causal (round-4 verified version) ----------
__global__ __launch_bounds__(512) void k_attn(
    const short* __restrict__ Q, const short* __restrict__ K,
    const short* __restrict__ Vt, short* __restrict__ ctx) {
  __shared__ short ks[2][4096];
  __shared__ short vs[2][4096];
  __shared__ short ps[8][16][72];
  const int tid = threadIdx.x;
  const int w = tid >> 6, l = tid & 63;
  const int lr = l & 15, lk = l >> 4;
  const int bh = blockIdx.y;
  const int bb = bh >> 4, hh = bh & 15;
  const size_t base = (size_t)bh * (SQ * HD);
  const float THR = 11.5416f;  // 8 * log2(e)

  const int srow = tid >> 3;
  const int scol = ((tid & 7) * 8) ^ ((srow & 7) * 8);
  const short* kg0 = K + base + srow * HD + scol;
  const short* vg0 = Vt + base + (size_t)srow * SQ + scol;
  short* kld = &ks[0][0] + tid * 8;
  short* vld = &vs[0][0] + tid * 8;
  const int rdswz = (lr & 7) * 8;

  int buf = 0;
  for (int pass = 0; pass < 2; ++pass) {
    const int qt = pass ? (15 - blockIdx.x) : blockIdx.x;
    const int nt = 2 * qt + 2;
    const int diag = 2 * qt + (w >> 2);
    const int qr = qt * 128 + w * 16;

    bf16x8 qf[2];
#pragma unroll
    for (int kk = 0; kk < 2; ++kk)
      qf[kk] = *(const bf16x8*)(Q + base + (size_t)(qr + lr) * HD + kk * 32 + lk * 8);

    f32x4 o[4] = {};
    float mrun = -3.0e4f, lsum = 0.f;

    gload_lds16(kg0, kld + buf * 4096);
    gload_lds16(vg0, vld + buf * 4096);
    __syncthreads();

    for (int t = 0; t < nt; ++t) {
      if (t + 1 < nt) {
        gload_lds16(kg0 + (t + 1) * 4096, kld + (buf ^ 1) * 4096);
        gload_lds16(vg0 + (t + 1) * 64, vld + (buf ^ 1) * 4096);
      }
      if (t <= diag) {
        const short* kb = &ks[buf][0];
        const short* vb = &vs[buf][0];
        f32x4 sf[4] = {};
        __builtin_amdgcn_s_setprio(1);
#pragma unroll
        for (int kk = 0; kk < 2; ++kk)
#pragma unroll
          for (int n = 0; n < 4; ++n) {
            bf16x8 kf = *(const bf16x8*)(kb + (n * 16 + lr) * 64 + ((kk * 32 + lk * 8) ^ rdswz));
            sf[n] = __builtin_amdgcn_mfma_f32_16x16x32_bf16(kf, qf[kk], sf[n], 0, 0, 0);
          }
        __builtin_amdgcn_s_setprio(0);

        if (t == diag) {
          const int qg = qr + lr;
#pragma unroll
          for (int n = 0; n < 4; ++n) {
            int kg = t * 64 + n * 16 + lk * 4;
#pragma unroll
            for (int r = 0; r < 4; ++r)
              if (kg + r > qg) sf[n][r] = -14426.95f;  // -10000 * log2(e)
          }
        }

        float m0 = sf[0][0];
#pragma unroll
        for (int n = 0; n < 4; ++n)
#pragma unroll
          for (int r = 0; r < 4; ++r) m0 = fmaxf(m0, sf[n][r]);
        m0 = fmaxf(m0, __shfl_xor(m0, 16));
        m0 = fmaxf(m0, __shfl_xor(m0, 32));

        if (__any(m0 > mrun + THR)) {
          float mn = fmaxf(mrun, m0);
          float sc = fexp2(mrun - mn);
          float scq[4];
#pragma unroll
          for (int r = 0; r < 4; ++r) scq[r] = __shfl(sc, lk * 4 + r);
#pragma unroll
          for (int nd = 0; nd < 4; ++nd)
#pragma unroll
            for (int r = 0; r < 4; ++r) o[nd][r] *= scq[r];
          lsum *= sc;
          mrun = mn;
        }

        float rs = 0.f;
#pragma unroll
        for (int n = 0; n < 4; ++n) {
          s16x4 pk;
#pragma unroll
          for (int r = 0; r < 4; ++r) {
            float p = fexp2(sf[n][r] - mrun);
            rs += p;
            pk[r] = (short)(__float_as_uint(p) >> 16);
          }
          *(s16x4*)&ps[w][lr][n * 16 + lk * 4] = pk;
        }
        lsum += rs;

        bf16x8 pa[2];
#pragma unroll
        for (int kk = 0; kk < 2; ++kk)
          pa[kk] = *(const bf16x8*)&ps[w][lr][kk * 32 + lk * 8];

        __builtin_amdgcn_s_setprio(1);
#pragma unroll
        for (int kk = 0; kk < 2; ++kk)
#pragma unroll
          for (int nd = 0; nd < 4; ++nd) {
            bf16x8 vf = *(const bf16x8*)(vb + (nd * 16 + lr) * 64 + ((kk * 32 + lk * 8) ^ rdswz));
            o[nd] = __builtin_amdgcn_mfma_f32_16x16x32_bf16(pa[kk], vf, o[nd], 0, 0, 0);
          }
        __builtin_amdgcn_s_setprio(0);
      }
      __syncthreads();
      buf ^= 1;
    }

    lsum += __shfl_xor(lsum, 16);
    lsum += __shfl_xor(lsum, 32);
    float inv = 1.0f / lsum;
    float invq[4];
#pragma unroll
    for (int r = 0; r < 4; ++r) invq[r] = __shfl(inv, lk * 4 + r);
#pragma unroll
    for (int nd = 0; nd < 4; ++nd)
#pragma unroll
      for (int r = 0; r < 4; ++r) {
        int s = qr + lk * 4 + r;
        ctx[((size_t)(bb * SQ + s)) * HID + hh * 64 + nd * 16 + lr] = f2bf(o[nd][r] * invq[r]);
      }
  }
}

extern "C" void kernel_launch(void* const* d_in, const int* in_sizes, int n_in,
                              void* d_out, int out_size, void* d_ws, size_t ws_size,
                              hipStream_t stream) {
  const float* hs   = (const float*)d_in[0];
  const float* wqkv = (const float*)d_in[1];
  const float* bqkv = (const float*)d_in[2];
  const float* wd   = (const float*)d_in[3];
  const float* bd   = (const float*)d_in[4];
  float* out = (float*)d_out;
  char* ws = (char*)d_ws;
  const size_t MB = 1u << 20;

  short* hs_bf  = (short*)(ws);            // 16 MB
  short* wqkv_t = (short*)(ws + 16 * MB);  //  6 MB
  short* wd_t   = (short*)(ws + 22 * MB);  //  2 MB
  short* qbuf   = (short*)(ws + 24 * MB);  // 16 MB: [64][2048][64]
  short* kbuf   = (short*)(ws + 40 * MB);  // 16 MB: [64][2048][64]
  short* vtbuf  = (short*)(ws + 56 * MB);  // 16 MB: [64][64][2048]
  short* ctx    = (short*)(ws + 72 * MB);  // 16 MB: [8192][1024]

  k_cvt<<<8192, 256, 0, stream>>>(hs, hs_bf, MTOK * HID / 4);
  k_tr<<<dim3(96, 32), dim3(32, 8), 0, stream>>>(wqkv, wqkv_t, 1024, 3072);
  k_tr<<<dim3(32, 32), dim3(32, 8), 0, stream>>>(wd, wd_t, 1024, 1024);
  k_gemm<0><<<dim3(24, 32), 512, 0, stream>>>(hs_bf, wqkv_t, bqkv,
                                              qbuf, kbuf, vtbuf, nullptr, 1024);
  k_attn<<<dim3(8, 64), 512, 0, stream>>>(qbuf, kbuf, vtbuf, ctx);
  k_gemm<1><<<dim3(8, 32), 512, 0, stream>>>(ctx, wd_t, bd,
                                             nullptr, nullptr, nullptr, out, 1024);
}

// Round 8
// 181.985 us; speedup vs baseline: 1.0173x; 1.0173x over previous
//
#include <hip/hip_runtime.h>

#define H_NUM 16
#define HD    64
#define SQ    2048
#define HID   1024
#define MTOK  8192   // B*S

typedef __attribute__((ext_vector_type(8))) short bf16x8;
typedef __attribute__((ext_vector_type(4))) short s16x4;
typedef __attribute__((ext_vector_type(4))) float f32x4;

__device__ __forceinline__ short f2bf(float f) {
  union { float f; unsigned u; } v; v.f = f;
  unsigned r = v.u + 0x7fffu + ((v.u >> 16) & 1u);
  return (short)(r >> 16);
}

__device__ __forceinline__ float fexp2(float x) {
#if __has_builtin(__builtin_amdgcn_exp2f)
  return __builtin_amdgcn_exp2f(x);
#else
  return exp2f(x);
#endif
}

__device__ __forceinline__ void gload_lds16(const short* g, short* l) {
  __builtin_amdgcn_global_load_lds(
      (const __attribute__((address_space(1))) void*)g,
      (__attribute__((address_space(3))) void*)l, 16, 0, 0);
}

// ---------- converters ----------
__global__ void k_cvt(const float* __restrict__ in, short* __restrict__ out, int n4) {
  int i = blockIdx.x * blockDim.x + threadIdx.x;
  if (i < n4) {
    float4 f = ((const float4*)in)[i];
    s16x4 o = { f2bf(f.x), f2bf(f.y), f2bf(f.z), f2bf(f.w) };
    ((s16x4*)out)[i] = o;
  }
}

// out[c][r] = bf16(in[r][c]);  R,C multiples of 32; block (32,8)
__global__ void k_tr(const float* __restrict__ in, short* __restrict__ out, int R, int C) {
  __shared__ float t[32][33];
  int c0 = blockIdx.x * 32, r0 = blockIdx.y * 32;
  int tx = threadIdx.x, ty = threadIdx.y;
#pragma unroll
  for (int i = 0; i < 4; i++)
    t[ty + 8 * i][tx] = in[(size_t)(r0 + ty + 8 * i) * C + c0 + tx];
  __syncthreads();
#pragma unroll
  for (int i = 0; i < 4; i++)
    out[(size_t)(c0 + ty + 8 * i) * R + r0 + tx] = f2bf(t[tx][ty + 8 * i]);
}

// ---------- GEMM: C[M,N] = A[M,K] @ Bt[N,K]^T + bias ----------
// r4-verified m97-style 128x128 (structure-capped ~650 TF @ K=1024).
template <int EPI>
__global__ __launch_bounds__(256) void k_gemm(
    const short* __restrict__ A, const short* __restrict__ Bt,
    const float* __restrict__ bias,
    short* __restrict__ qbuf, short* __restrict__ kbuf, short* __restrict__ vtbuf,
    float* __restrict__ outf, int Kd) {
  __shared__ short as[128][64];
  __shared__ short bs[128][64];
  const int tid = threadIdx.x;
  const int w = tid >> 6, l = tid & 63;
  const int lr = l & 15, lk = l >> 4;
  const int wr = w >> 1, wc = w & 1;
  // bijective XCD swizzle (nwg % 8 == 0 for both launches)
  const int nwg = gridDim.x * gridDim.y;
  const int lin = blockIdx.y * gridDim.x + blockIdx.x;
  const int swz = (lin & 7) * (nwg >> 3) + (lin >> 3);
  const int m0 = (swz / gridDim.x) * 128, n0 = (swz % gridDim.x) * 128;

  f32x4 acc[4][4] = {};

  for (int kt = 0; kt < Kd; kt += 64) {
#pragma unroll
    for (int rnd = 0; rnd < 4; ++rnd) {
      int e = rnd * 2048 + w * 512 + l * 8;
      int row = e >> 6, col = e & 63;
      gload_lds16(A + (size_t)(m0 + row) * Kd + kt + col,
                  &as[0][0] + rnd * 2048 + w * 512);
      gload_lds16(Bt + (size_t)(n0 + row) * Kd + kt + col,
                  &bs[0][0] + rnd * 2048 + w * 512);
    }
    __syncthreads();
#pragma unroll
    for (int kk = 0; kk < 2; ++kk) {
      bf16x8 af[4], bf[4];
#pragma unroll
      for (int m = 0; m < 4; ++m)
        af[m] = *(const bf16x8*)&as[wr * 64 + m * 16 + lr][kk * 32 + lk * 8];
#pragma unroll
      for (int n = 0; n < 4; ++n)
        bf[n] = *(const bf16x8*)&bs[wc * 64 + n * 16 + lr][kk * 32 + lk * 8];
      __builtin_amdgcn_s_setprio(1);
#pragma unroll
      for (int m = 0; m < 4; ++m)
#pragma unroll
        for (int n = 0; n < 4; ++n)
          acc[m][n] = __builtin_amdgcn_mfma_f32_16x16x32_bf16(af[m], bf[n], acc[m][n], 0, 0, 0);
      __builtin_amdgcn_s_setprio(0);
    }
    __syncthreads();
  }

  // C layout: col=lane&15, row=(lane>>4)*4+reg  [m89]
  const float SCLQ = 0.125f * 1.44269504088896341f;
#pragma unroll
  for (int n = 0; n < 4; ++n) {
    const int col = n0 + wc * 64 + n * 16 + lr;
    const float bv = bias[col];
    if (EPI == 1) {
#pragma unroll
      for (int m = 0; m < 4; ++m) {
        int row = m0 + wr * 64 + m * 16 + lk * 4;
#pragma unroll
        for (int r = 0; r < 4; ++r)
          outf[(size_t)(row + r) * HID + col] = acc[m][n][r] + bv;
      }
    } else if (col < HID) {  // K: [BH][S][D]
      int h = col >> 6, d = col & 63;
#pragma unroll
      for (int m = 0; m < 4; ++m) {
        int row = m0 + wr * 64 + m * 16 + lk * 4;
        int b = row >> 11, s = row & 2047;
#pragma unroll
        for (int r = 0; r < 4; ++r)
          kbuf[((size_t)(b * H_NUM + h) * SQ + s + r) * HD + d] = f2bf(acc[m][n][r] + bv);
      }
    } else if (col < 2 * HID) {  // V^T: [BH][D][S], packed 4-s stores
      int f = col - HID, h = f >> 6, d = f & 63;
#pragma unroll
      for (int m = 0; m < 4; ++m) {
        int row = m0 + wr * 64 + m * 16 + lk * 4;
        int b = row >> 11, s = row & 2047;
        s16x4 pk;
#pragma unroll
        for (int r = 0; r < 4; ++r) pk[r] = f2bf(acc[m][n][r] + bv);
        *(s16x4*)&vtbuf[((size_t)(b * H_NUM + h) * HD + d) * SQ + s] = pk;
      }
    } else {  // Q: [BH][S][D], pre-scaled into exp2 domain
      int f = col - 2 * HID, h = f >> 6, d = f & 63;
#pragma unroll
      for (int m = 0; m < 4; ++m) {
        int row = m0 + wr * 64 + m * 16 + lk * 4;
        int b = row >> 11, s = row & 2047;
#pragma unroll
        for (int r = 0; r < 4; ++r)
          qbuf[((size_t)(b * H_NUM + h) * SQ + s + r) * HD + d] = f2bf((acc[m][n][r] + bv) * SCLQ);
      }
    }
  }
}

// ---------- flash attention, causal ----------
// grid (8, B*H), block 256 = 4 waves; each wave owns TWO 16-row strips
// (rows w*16 and 64+w*16 of a 128-row q-tile) -> K/V fragments loaded into
// registers ONCE per tile, reused by both strips (frag reads per q-row halved).
// q-tile pair {a, 15-a} per block (balance); K/V double-buffered swizzled LDS.
// Swapped QK^T + in-lane softmax + defer-rescale (r4-verified core).
__global__ __launch_bounds__(256, 2) void k_attn(
    const short* __restrict__ Q, const short* __restrict__ K,
    const short* __restrict__ Vt, short* __restrict__ ctx) {
  __shared__ short ks[2][4096];
  __shared__ short vs[2][4096];
  __shared__ short ps[4][16][72];
  const int tid = threadIdx.x;
  const int w = tid >> 6, l = tid & 63;
  const int lr = l & 15, lk = l >> 4;
  const int bh = blockIdx.y;
  const int bb = bh >> 4, hh = bh & 15;
  const size_t base = (size_t)bh * (SQ * HD);
  const float THR = 11.5416f;  // 8 * log2(e)

  // staging: 2 granules each of K and V per thread (256 thr x 4 x 16B = 16KB)
  const int r0 = tid >> 3;
  const int scol = ((tid & 7) * 8) ^ ((r0 & 7) * 8);
  const short* kga = K + base + (size_t)r0 * HD + scol;
  const short* kgb = kga + 32 * HD;
  const short* vga = Vt + base + (size_t)r0 * SQ + scol;
  const short* vgb = vga + (size_t)32 * SQ;
  short* klda = &ks[0][0] + tid * 8;
  short* kldb = &ks[0][0] + (tid + 256) * 8;
  short* vlda = &vs[0][0] + tid * 8;
  short* vldb = &vs[0][0] + (tid + 256) * 8;
  const int rdswz = (lr & 7) * 8;

  int buf = 0;
  for (int pass = 0; pass < 2; ++pass) {
    const int qt = pass ? (15 - blockIdx.x) : blockIdx.x;
    const int nt = 2 * qt + 2;
    const int d0 = 2 * qt;               // strip st's diag tile = d0 + st

    bf16x8 qf[2][2];
#pragma unroll
    for (int st = 0; st < 2; ++st)
#pragma unroll
      for (int kk = 0; kk < 2; ++kk)
        qf[st][kk] = *(const bf16x8*)(Q + base +
            (size_t)(qt * 128 + st * 64 + w * 16 + lr) * HD + kk * 32 + lk * 8);

    f32x4 o[2][4] = {};
    float mrun[2] = {-3.0e4f, -3.0e4f}, lsum[2] = {0.f, 0.f};

    // prologue: stage tile 0
    gload_lds16(kga, klda + buf * 4096); gload_lds16(kgb, kldb + buf * 4096);
    gload_lds16(vga, vlda + buf * 4096); gload_lds16(vgb, vldb + buf * 4096);
    __syncthreads();

    for (int t = 0; t < nt; ++t) {
      if (t + 1 < nt) {  // stage next tile (overlaps compute)
        const int lo = (buf ^ 1) * 4096;
        const int gk = (t + 1) * 4096, gv = (t + 1) * 64;
        gload_lds16(kga + gk, klda + lo); gload_lds16(kgb + gk, kldb + lo);
        gload_lds16(vga + gv, vlda + lo); gload_lds16(vgb + gv, vldb + lo);
      }
      {
        const short* kb = &ks[buf][0];
        const short* vb = &vs[buf][0];
        // K and V fragments: loaded once, reused by both strips
        bf16x8 kf[2][4], vf[2][4];
#pragma unroll
        for (int kk = 0; kk < 2; ++kk)
#pragma unroll
          for (int n = 0; n < 4; ++n) {
            kf[kk][n] = *(const bf16x8*)(kb + (n * 16 + lr) * 64 + ((kk * 32 + lk * 8) ^ rdswz));
            vf[kk][n] = *(const bf16x8*)(vb + (n * 16 + lr) * 64 + ((kk * 32 + lk * 8) ^ rdswz));
          }

#pragma unroll
        for (int st = 0; st < 2; ++st) {
          if (t <= d0 + st) {
            // S^T = K @ Q'^T : sf[n][r] = S[k=t*64+n*16+lk*4+r][q]
            f32x4 sf[4] = {};
            __builtin_amdgcn_s_setprio(1);
#pragma unroll
            for (int kk = 0; kk < 2; ++kk)
#pragma unroll
              for (int n = 0; n < 4; ++n)
                sf[n] = __builtin_amdgcn_mfma_f32_16x16x32_bf16(kf[kk][n], qf[st][kk], sf[n], 0, 0, 0);
            __builtin_amdgcn_s_setprio(0);

            if (t == d0 + st) {  // diagonal mask
              const int qg = w * 16 + lr;  // q, k compared within the tile
#pragma unroll
              for (int n = 0; n < 4; ++n) {
                int kg = n * 16 + lk * 4;
#pragma unroll
                for (int r = 0; r < 4; ++r)
                  if (kg + r > qg) sf[n][r] = -14426.95f;  // -10000 * log2(e)
              }
            }

            // in-lane row max, then across the lk group
            float m0 = sf[0][0];
#pragma unroll
            for (int n = 0; n < 4; ++n)
#pragma unroll
              for (int r = 0; r < 4; ++r) m0 = fmaxf(m0, sf[n][r]);
            m0 = fmaxf(m0, __shfl_xor(m0, 16));
            m0 = fmaxf(m0, __shfl_xor(m0, 32));

            if (__any(m0 > mrun[st] + THR)) {  // T13 defer-rescale (rare)
              float mn = fmaxf(mrun[st], m0);
              float sc = fexp2(mrun[st] - mn);
              float scq[4];
#pragma unroll
              for (int r = 0; r < 4; ++r) scq[r] = __shfl(sc, lk * 4 + r);
#pragma unroll
              for (int nd = 0; nd < 4; ++nd)
#pragma unroll
                for (int r = 0; r < 4; ++r) o[st][nd][r] *= scq[r];
              lsum[st] *= sc;
              mrun[st] = mn;
            }

            // P = exp2(S' - mrun); packed b64 writes; per-lane partial lsum
            float rs = 0.f;
#pragma unroll
            for (int n = 0; n < 4; ++n) {
              s16x4 pk;
#pragma unroll
              for (int r = 0; r < 4; ++r) {
                float p = fexp2(sf[n][r] - mrun[st]);
                rs += p;
                pk[r] = (short)(__float_as_uint(p) >> 16);
              }
              *(s16x4*)&ps[w][lr][n * 16 + lk * 4] = pk;
            }
            lsum[st] += rs;

            // reload P as MFMA A-fragment (same-wave LDS roundtrip)
            bf16x8 pa[2];
#pragma unroll
            for (int kk = 0; kk < 2; ++kk)
              pa[kk] = *(const bf16x8*)&ps[w][lr][kk * 32 + lk * 8];

            // O += P @ V
            __builtin_amdgcn_s_setprio(1);
#pragma unroll
            for (int kk = 0; kk < 2; ++kk)
#pragma unroll
              for (int nd = 0; nd < 4; ++nd)
                o[st][nd] = __builtin_amdgcn_mfma_f32_16x16x32_bf16(pa[kk], vf[kk][nd], o[st][nd], 0, 0, 0);
            __builtin_amdgcn_s_setprio(0);
          }
        }
      }
      __syncthreads();  // drains staging vmcnt + protects buf swap
      buf ^= 1;
    }

    // epilogue per strip
#pragma unroll
    for (int st = 0; st < 2; ++st) {
      float ls = lsum[st];
      ls += __shfl_xor(ls, 16);
      ls += __shfl_xor(ls, 32);
      float inv = 1.0f / ls;
      float invq[4];
#pragma unroll
      for (int r = 0; r < 4; ++r) invq[r] = __shfl(inv, lk * 4 + r);
#pragma unroll
      for (int nd = 0; nd < 4; ++nd)
#pragma unroll
        for (int r = 0; r < 4; ++r) {
          int s = qt * 128 + st * 64 + w * 16 + lk * 4 + r;
          ctx[((size_t)(bb * SQ + s)) * HID + hh * 64 + nd * 16 + lr] =
              f2bf(o[st][nd][r] * invq[r]);
        }
    }
  }
}

extern "C" void kernel_launch(void* const* d_in, const int* in_sizes, int n_in,
                              void* d_out, int out_size, void* d_ws, size_t ws_size,
                              hipStream_t stream) {
  const float* hs   = (const float*)d_in[0];
  const float* wqkv = (const float*)d_in[1];
  const float* bqkv = (const float*)d_in[2];
  const float* wd   = (const float*)d_in[3];
  const float* bd   = (const float*)d_in[4];
  float* out = (float*)d_out;
  char* ws = (char*)d_ws;
  const size_t MB = 1u << 20;

  short* hs_bf  = (short*)(ws);            // 16 MB
  short* wqkv_t = (short*)(ws + 16 * MB);  //  6 MB
  short* wd_t   = (short*)(ws + 22 * MB);  //  2 MB
  short* qbuf   = (short*)(ws + 24 * MB);  // 16 MB: [64][2048][64]
  short* kbuf   = (short*)(ws + 40 * MB);  // 16 MB: [64][2048][64]
  short* vtbuf  = (short*)(ws + 56 * MB);  // 16 MB: [64][64][2048]
  short* ctx    = (short*)(ws + 72 * MB);  // 16 MB: [8192][1024]

  k_cvt<<<8192, 256, 0, stream>>>(hs, hs_bf, MTOK * HID / 4);
  k_tr<<<dim3(96, 32), dim3(32, 8), 0, stream>>>(wqkv, wqkv_t, 1024, 3072);
  k_tr<<<dim3(32, 32), dim3(32, 8), 0, stream>>>(wd, wd_t, 1024, 1024);
  k_gemm<0><<<dim3(24, 64), 256, 0, stream>>>(hs_bf, wqkv_t, bqkv,
                                              qbuf, kbuf, vtbuf, nullptr, 1024);
  k_attn<<<dim3(8, 64), 256, 0, stream>>>(qbuf, kbuf, vtbuf, ctx);
  k_gemm<1><<<dim3(8, 64), 256, 0, stream>>>(ctx, wd_t, bd,
                                             nullptr, nullptr, nullptr, out, 1024);
}

// Round 9
// 170.094 us; speedup vs baseline: 1.0885x; 1.0699x over previous
//
#include <hip/hip_runtime.h>

#define H_NUM 16
#define HD    64
#define SQ    2048
#define HID   1024
#define MTOK  8192   // B*S

typedef __attribute__((ext_vector_type(8))) short bf16x8;
typedef __attribute__((ext_vector_type(4))) short s16x4;
typedef __attribute__((ext_vector_type(4))) float f32x4;

__device__ __forceinline__ short f2bf(float f) {
  union { float f; unsigned u; } v; v.f = f;
  unsigned r = v.u + 0x7fffu + ((v.u >> 16) & 1u);
  return (short)(r >> 16);
}

__device__ __forceinline__ float fexp2(float x) {
#if __has_builtin(__builtin_amdgcn_exp2f)
  return __builtin_amdgcn_exp2f(x);
#else
  return exp2f(x);
#endif
}

__device__ __forceinline__ void gload_lds16(const short* g, short* l) {
  __builtin_amdgcn_global_load_lds(
      (const __attribute__((address_space(1))) void*)g,
      (__attribute__((address_space(3))) void*)l, 16, 0, 0);
}

// ---------- converters ----------
__global__ void k_cvt(const float* __restrict__ in, short* __restrict__ out, int n4) {
  int i = blockIdx.x * blockDim.x + threadIdx.x;
  if (i < n4) {
    float4 f = ((const float4*)in)[i];
    s16x4 o = { f2bf(f.x), f2bf(f.y), f2bf(f.z), f2bf(f.w) };
    ((s16x4*)out)[i] = o;
  }
}

// out[c][r] = bf16(in[r][c]);  R,C multiples of 32; block (32,8)
__global__ void k_tr(const float* __restrict__ in, short* __restrict__ out, int R, int C) {
  __shared__ float t[32][33];
  int c0 = blockIdx.x * 32, r0 = blockIdx.y * 32;
  int tx = threadIdx.x, ty = threadIdx.y;
#pragma unroll
  for (int i = 0; i < 4; i++)
    t[ty + 8 * i][tx] = in[(size_t)(r0 + ty + 8 * i) * C + c0 + tx];
  __syncthreads();
#pragma unroll
  for (int i = 0; i < 4; i++)
    out[(size_t)(c0 + ty + 8 * i) * R + r0 + tx] = f2bf(t[tx][ty + 8 * i]);
}

// ---------- GEMM: C[M,N] = A[M,K] @ Bt[N,K]^T + bias ----------
// r4-verified m97-style 128x128 (structure-capped ~650 TF @ K=1024).
template <int EPI>
__global__ __launch_bounds__(256) void k_gemm(
    const short* __restrict__ A, const short* __restrict__ Bt,
    const float* __restrict__ bias,
    short* __restrict__ qbuf, short* __restrict__ kbuf, short* __restrict__ vtbuf,
    float* __restrict__ outf, int Kd) {
  __shared__ short as[128][64];
  __shared__ short bs[128][64];
  const int tid = threadIdx.x;
  const int w = tid >> 6, l = tid & 63;
  const int lr = l & 15, lk = l >> 4;
  const int wr = w >> 1, wc = w & 1;
  // bijective XCD swizzle (nwg % 8 == 0 for both launches)
  const int nwg = gridDim.x * gridDim.y;
  const int lin = blockIdx.y * gridDim.x + blockIdx.x;
  const int swz = (lin & 7) * (nwg >> 3) + (lin >> 3);
  const int m0 = (swz / gridDim.x) * 128, n0 = (swz % gridDim.x) * 128;

  f32x4 acc[4][4] = {};

  for (int kt = 0; kt < Kd; kt += 64) {
#pragma unroll
    for (int rnd = 0; rnd < 4; ++rnd) {
      int e = rnd * 2048 + w * 512 + l * 8;
      int row = e >> 6, col = e & 63;
      gload_lds16(A + (size_t)(m0 + row) * Kd + kt + col,
                  &as[0][0] + rnd * 2048 + w * 512);
      gload_lds16(Bt + (size_t)(n0 + row) * Kd + kt + col,
                  &bs[0][0] + rnd * 2048 + w * 512);
    }
    __syncthreads();
#pragma unroll
    for (int kk = 0; kk < 2; ++kk) {
      bf16x8 af[4], bf[4];
#pragma unroll
      for (int m = 0; m < 4; ++m)
        af[m] = *(const bf16x8*)&as[wr * 64 + m * 16 + lr][kk * 32 + lk * 8];
#pragma unroll
      for (int n = 0; n < 4; ++n)
        bf[n] = *(const bf16x8*)&bs[wc * 64 + n * 16 + lr][kk * 32 + lk * 8];
      __builtin_amdgcn_s_setprio(1);
#pragma unroll
      for (int m = 0; m < 4; ++m)
#pragma unroll
        for (int n = 0; n < 4; ++n)
          acc[m][n] = __builtin_amdgcn_mfma_f32_16x16x32_bf16(af[m], bf[n], acc[m][n], 0, 0, 0);
      __builtin_amdgcn_s_setprio(0);
    }
    __syncthreads();
  }

  // C layout: col=lane&15, row=(lane>>4)*4+reg  [m89]
  const float SCLQ = 0.125f * 1.44269504088896341f;
#pragma unroll
  for (int n = 0; n < 4; ++n) {
    const int col = n0 + wc * 64 + n * 16 + lr;
    const float bv = bias[col];
    if (EPI == 1) {
#pragma unroll
      for (int m = 0; m < 4; ++m) {
        int row = m0 + wr * 64 + m * 16 + lk * 4;
#pragma unroll
        for (int r = 0; r < 4; ++r)
          outf[(size_t)(row + r) * HID + col] = acc[m][n][r] + bv;
      }
    } else if (col < HID) {  // K: [BH][S][D]
      int h = col >> 6, d = col & 63;
#pragma unroll
      for (int m = 0; m < 4; ++m) {
        int row = m0 + wr * 64 + m * 16 + lk * 4;
        int b = row >> 11, s = row & 2047;
#pragma unroll
        for (int r = 0; r < 4; ++r)
          kbuf[((size_t)(b * H_NUM + h) * SQ + s + r) * HD + d] = f2bf(acc[m][n][r] + bv);
      }
    } else if (col < 2 * HID) {  // V^T: [BH][D][S], packed 4-s stores
      int f = col - HID, h = f >> 6, d = f & 63;
#pragma unroll
      for (int m = 0; m < 4; ++m) {
        int row = m0 + wr * 64 + m * 16 + lk * 4;
        int b = row >> 11, s = row & 2047;
        s16x4 pk;
#pragma unroll
        for (int r = 0; r < 4; ++r) pk[r] = f2bf(acc[m][n][r] + bv);
        *(s16x4*)&vtbuf[((size_t)(b * H_NUM + h) * HD + d) * SQ + s] = pk;
      }
    } else {  // Q: [BH][S][D], pre-scaled into exp2 domain
      int f = col - 2 * HID, h = f >> 6, d = f & 63;
#pragma unroll
      for (int m = 0; m < 4; ++m) {
        int row = m0 + wr * 64 + m * 16 + lk * 4;
        int b = row >> 11, s = row & 2047;
#pragma unroll
        for (int r = 0; r < 4; ++r)
          qbuf[((size_t)(b * H_NUM + h) * SQ + s + r) * HD + d] = f2bf((acc[m][n][r] + bv) * SCLQ);
      }
    }
  }
}

// ---------- flash attention, causal ----------
// ONE 128-row q-tile per block (grid 1024 = 4 blocks/CU nominal, 3 by LDS),
// longest-first issue order inside XCD-bijective chunks (8 bh per XCD).
// 8 waves x 16 q-rows; K/V double-buffered swizzled LDS via global_load_lds.
// Swapped QK^T (lane owns q-row) -> in-lane softmax, defer-rescale,
// packed b64 P writes, lsum reduced once at end.  [r4-verified core]
__global__ __launch_bounds__(512) void k_attn(
    const short* __restrict__ Q, const short* __restrict__ K,
    const short* __restrict__ Vt, short* __restrict__ ctx) {
  __shared__ short ks[2][4096];
  __shared__ short vs[2][4096];
  __shared__ short ps[8][16][72];
  const int tid = threadIdx.x;
  const int w = tid >> 6, l = tid & 63;
  const int lr = l & 15, lk = l >> 4;

  // lin -> (xcd, bh', q') with qt descending as primary issue order:
  // lin 0..63 = qt15 for all 64 bh, then qt14, ...
  const int lin = blockIdx.x;          // 0..1023
  const int xcd = lin & 7;
  const int idx = lin >> 3;            // 0..127
  const int qt  = 15 - (idx >> 3);     // longest first
  const int bh  = xcd * 8 + (idx & 7); // 8 bh per XCD chunk (4MB K+V in L2)
  const int bb = bh >> 4, hh = bh & 15;
  const size_t base = (size_t)bh * (SQ * HD);
  const float THR = 11.5416f;  // 8 * log2(e)

  const int nt = 2 * qt + 2;
  const int diag = 2 * qt + (w >> 2);  // wave-uniform diagonal tile
  const int qr = qt * 128 + w * 16;

  // staging: thread owns one 16B granule; source column pre-swizzled
  const int srow = tid >> 3;
  const int scol = ((tid & 7) * 8) ^ ((srow & 7) * 8);
  const short* kg0 = K + base + srow * HD + scol;
  const short* vg0 = Vt + base + (size_t)srow * SQ + scol;
  short* kld = &ks[0][0] + tid * 8;
  short* vld = &vs[0][0] + tid * 8;
  const int rdswz = (lr & 7) * 8;

  bf16x8 qf[2];
#pragma unroll
  for (int kk = 0; kk < 2; ++kk)
    qf[kk] = *(const bf16x8*)(Q + base + (size_t)(qr + lr) * HD + kk * 32 + lk * 8);

  f32x4 o[4] = {};
  float mrun = -3.0e4f, lsum = 0.f;  // per lane: q-row = qr + lr

  // prologue: stage tile 0
  int buf = 0;
  gload_lds16(kg0, kld);
  gload_lds16(vg0, vld);
  __syncthreads();

  for (int t = 0; t < nt; ++t) {
    if (t + 1 < nt) {  // stage next tile (overlaps compute)
      gload_lds16(kg0 + (t + 1) * 4096, kld + (buf ^ 1) * 4096);
      gload_lds16(vg0 + (t + 1) * 64, vld + (buf ^ 1) * 4096);
    }
    if (t <= diag) {
      const short* kb = &ks[buf][0];
      const short* vb = &vs[buf][0];
      // S^T = K @ Q'^T : sf[n][r] = S[k=t*64+n*16+lk*4+r][q=qr+lr]
      f32x4 sf[4] = {};
      __builtin_amdgcn_s_setprio(1);
#pragma unroll
      for (int kk = 0; kk < 2; ++kk)
#pragma unroll
        for (int n = 0; n < 4; ++n) {
          bf16x8 kf = *(const bf16x8*)(kb + (n * 16 + lr) * 64 + ((kk * 32 + lk * 8) ^ rdswz));
          sf[n] = __builtin_amdgcn_mfma_f32_16x16x32_bf16(kf, qf[kk], sf[n], 0, 0, 0);
        }
      __builtin_amdgcn_s_setprio(0);

      if (t == diag) {  // diagonal mask
        const int qg = qr + lr;
#pragma unroll
        for (int n = 0; n < 4; ++n) {
          int kg = t * 64 + n * 16 + lk * 4;
#pragma unroll
          for (int r = 0; r < 4; ++r)
            if (kg + r > qg) sf[n][r] = -14426.95f;  // -10000 * log2(e)
        }
      }

      // in-lane row max over 16 regs, then across the lk group
      float m0 = sf[0][0];
#pragma unroll
      for (int n = 0; n < 4; ++n)
#pragma unroll
        for (int r = 0; r < 4; ++r) m0 = fmaxf(m0, sf[n][r]);
      m0 = fmaxf(m0, __shfl_xor(m0, 16));
      m0 = fmaxf(m0, __shfl_xor(m0, 32));

      if (__any(m0 > mrun + THR)) {  // T13 defer-rescale (rare)
        float mn = fmaxf(mrun, m0);
        float sc = fexp2(mrun - mn);
        float scq[4];
#pragma unroll
        for (int r = 0; r < 4; ++r) scq[r] = __shfl(sc, lk * 4 + r);
#pragma unroll
        for (int nd = 0; nd < 4; ++nd)
#pragma unroll
          for (int r = 0; r < 4; ++r) o[nd][r] *= scq[r];
        lsum *= sc;
        mrun = mn;
      }

      // P = exp2(S' - mrun); packed b64 P writes; per-lane partial lsum
      float rs = 0.f;
#pragma unroll
      for (int n = 0; n < 4; ++n) {
        s16x4 pk;
#pragma unroll
        for (int r = 0; r < 4; ++r) {
          float p = fexp2(sf[n][r] - mrun);
          rs += p;
          pk[r] = (short)(__float_as_uint(p) >> 16);
        }
        *(s16x4*)&ps[w][lr][n * 16 + lk * 4] = pk;
      }
      lsum += rs;

      // reload P as MFMA A-fragment (same-wave LDS roundtrip)
      bf16x8 pa[2];
#pragma unroll
      for (int kk = 0; kk < 2; ++kk)
        pa[kk] = *(const bf16x8*)&ps[w][lr][kk * 32 + lk * 8];

      // O += P @ V
      __builtin_amdgcn_s_setprio(1);
#pragma unroll
      for (int kk = 0; kk < 2; ++kk)
#pragma unroll
        for (int nd = 0; nd < 4; ++nd) {
          bf16x8 vf = *(const bf16x8*)(vb + (nd * 16 + lr) * 64 + ((kk * 32 + lk * 8) ^ rdswz));
          o[nd] = __builtin_amdgcn_mfma_f32_16x16x32_bf16(pa[kk], vf, o[nd], 0, 0, 0);
        }
      __builtin_amdgcn_s_setprio(0);
    }
    __syncthreads();  // drains staging vmcnt + protects buf swap
    buf ^= 1;
  }

  // epilogue: reduce lsum across lk group once; o[nd][r] = O[qr+lk*4+r][nd*16+lr]
  lsum += __shfl_xor(lsum, 16);
  lsum += __shfl_xor(lsum, 32);
  float inv = 1.0f / lsum;
  float invq[4];
#pragma unroll
  for (int r = 0; r < 4; ++r) invq[r] = __shfl(inv, lk * 4 + r);
#pragma unroll
  for (int nd = 0; nd < 4; ++nd)
#pragma unroll
    for (int r = 0; r < 4; ++r) {
      int s = qr + lk * 4 + r;
      ctx[((size_t)(bb * SQ + s)) * HID + hh * 64 + nd * 16 + lr] = f2bf(o[nd][r] * invq[r]);
    }
}

extern "C" void kernel_launch(void* const* d_in, const int* in_sizes, int n_in,
                              void* d_out, int out_size, void* d_ws, size_t ws_size,
                              hipStream_t stream) {
  const float* hs   = (const float*)d_in[0];
  const float* wqkv = (const float*)d_in[1];
  const float* bqkv = (const float*)d_in[2];
  const float* wd   = (const float*)d_in[3];
  const float* bd   = (const float*)d_in[4];
  float* out = (float*)d_out;
  char* ws = (char*)d_ws;
  const size_t MB = 1u << 20;

  short* hs_bf  = (short*)(ws);            // 16 MB
  short* wqkv_t = (short*)(ws + 16 * MB);  //  6 MB
  short* wd_t   = (short*)(ws + 22 * MB);  //  2 MB
  short* qbuf   = (short*)(ws + 24 * MB);  // 16 MB: [64][2048][64]
  short* kbuf   = (short*)(ws + 40 * MB);  // 16 MB: [64][2048][64]
  short* vtbuf  = (short*)(ws + 56 * MB);  // 16 MB: [64][64][2048]
  short* ctx    = (short*)(ws + 72 * MB);  // 16 MB: [8192][1024]

  k_cvt<<<8192, 256, 0, stream>>>(hs, hs_bf, MTOK * HID / 4);
  k_tr<<<dim3(96, 32), dim3(32, 8), 0, stream>>>(wqkv, wqkv_t, 1024, 3072);
  k_tr<<<dim3(32, 32), dim3(32, 8), 0, stream>>>(wd, wd_t, 1024, 1024);
  k_gemm<0><<<dim3(24, 64), 256, 0, stream>>>(hs_bf, wqkv_t, bqkv,
                                              qbuf, kbuf, vtbuf, nullptr, 1024);
  k_attn<<<1024, 512, 0, stream>>>(qbuf, kbuf, vtbuf, ctx);
  k_gemm<1><<<dim3(8, 64), 256, 0, stream>>>(ctx, wd_t, bd,
                                             nullptr, nullptr, nullptr, out, 1024);
}